// Round 12
// baseline (15816.884 us; speedup 1.0000x reference)
//
#include <hip/hip_runtime.h>
#include <hip/hip_bf16.h>

#define T_STEPS 2048
#define HID 256
#define INF 72
#define OUTF 90
#define HSTR 528          // LDS h row stride for gi_mfma (bytes)

typedef __attribute__((ext_vector_type(4))) float f32x4;
typedef __attribute__((ext_vector_type(8))) short s16x8;
typedef unsigned long long u64;

__device__ __forceinline__ unsigned short f2bf(float f) {
  union { float f; unsigned u; } v; v.f = f;
  unsigned r = (v.u + 0x7FFFu + ((v.u >> 16) & 1u)) >> 16;   // RNE
  return (unsigned short)r;
}
__device__ __forceinline__ float bf2f(unsigned short s) {
  union { unsigned u; float f; } v; v.u = ((unsigned)s) << 16;
  return v.f;
}
__device__ __forceinline__ float sigm(float x) {
  return __builtin_amdgcn_rcpf(1.f + __builtin_amdgcn_exp2f(-1.44269504f * x));
}
__device__ __forceinline__ float tanh_f(float x) {
  return 1.f - 2.f * __builtin_amdgcn_rcpf(1.f + __builtin_amdgcn_exp2f(2.88539008f * x));
}

// ---- relaxed agent-scope (sc1) primitives — R8/R11-proven ----
__device__ __forceinline__ u64 ld64(const u64* p) {
  return __hip_atomic_load(p, __ATOMIC_RELAXED, __HIP_MEMORY_SCOPE_AGENT);
}
__device__ __forceinline__ void st64(u64* p, u64 v) {
  __hip_atomic_store(p, v, __ATOMIC_RELAXED, __HIP_MEMORY_SCOPE_AGENT);
}
__device__ __forceinline__ void stflag(unsigned* p, unsigned v) {
  __hip_atomic_store(p, v, __ATOMIC_RELAXED, __HIP_MEMORY_SCOPE_AGENT);
}
__device__ __forceinline__ unsigned wait2(const unsigned* creds, unsigned target, unsigned cred) {
  const u64* cp = (const u64*)creds;
  while (cred < target) {
    u64 v = ld64(cp);
    unsigned a = (unsigned)v, b = (unsigned)(v >> 32);
    cred = a < b ? a : b;
    if (cred < target) __builtin_amdgcn_s_sleep(2);
  }
  return cred;
}
// plain cached 32B gi record (producer drained + credited before we read)
__device__ __forceinline__ void ld_g(const unsigned short* p, s16x8& a, s16x8& b) {
  a = *(const s16x8*)p; b = *(const s16x8*)(p + 8);
}

// ---------------- input projection: h0 = relu(x @ W1^T + b1) ----------------
__global__ __launch_bounds__(256) void inproj(const float* __restrict__ x,
                                              const float* __restrict__ W1,
                                              const float* __restrict__ b1,
                                              float* __restrict__ h0) {
  __shared__ float w1s[HID][INF + 1];
  __shared__ float xs[16][INF];
  const int tid = threadIdx.x;
  const int r0 = blockIdx.x * 16;
  for (int i = tid; i < HID * INF; i += 256) w1s[i / INF][i % INF] = W1[i];
  for (int i = tid; i < 16 * INF; i += 256)
    xs[i / INF][i % INF] = x[(size_t)(r0 + i / INF) * INF + (i % INF)];
  __syncthreads();
  const float bj = b1[tid];
  for (int r = 0; r < 16; ++r) {
    float acc = bj;
#pragma unroll 8
    for (int k = 0; k < INF; ++k) acc += xs[r][k] * w1s[tid][k];
    h0[(size_t)(r0 + r) * HID + tid] = fmaxf(acc, 0.f);
  }
}

// ---------------- pack f32 -> bf16 ----------------
__global__ __launch_bounds__(256) void wpack(const float* __restrict__ w,
                                             unsigned short* __restrict__ o) {
  const size_t i = ((size_t)blockIdx.x * 256 + threadIdx.x) * 8;
  f32x4 a = *(const f32x4*)(w + i);
  f32x4 b = *(const f32x4*)(w + i + 4);
  s16x8 v;
#pragma unroll
  for (int e = 0; e < 4; ++e) { v[e] = (short)f2bf(a[e]); v[4 + e] = (short)f2bf(b[e]); }
  *(s16x8*)(o + i) = v;
}

// ------------- layer-1 gi GEMM (MFMA, swapped orientation): one block per t -------------
__global__ __launch_bounds__(256) void gi_mfma(const float* __restrict__ h,
                                               const unsigned short* __restrict__ wb,
                                               const float* __restrict__ bih,
                                               const float* __restrict__ bhh,
                                               unsigned short* __restrict__ gi) {
  __shared__ __align__(16) char hs[16 * HSTR];
  __shared__ float bs[1024];
  const int tid = threadIdx.x;
  const int t = blockIdx.x;
  const int lane = tid & 63;
  const int wg = tid >> 6;
  const int j = lane & 15;
  const int hi = lane >> 4;
  for (int i = tid; i < 1024; i += 256) bs[i] = bih[i] + bhh[i];
  {
    const int row = tid >> 4;
    const int c0 = (tid & 15) * 16;
    const float* src = h + ((size_t)t * 16 + row) * 256 + c0;
    f32x4 v0 = *(const f32x4*)(src);
    f32x4 v1 = *(const f32x4*)(src + 4);
    f32x4 v2 = *(const f32x4*)(src + 8);
    f32x4 v3 = *(const f32x4*)(src + 12);
    s16x8 p0, p1;
#pragma unroll
    for (int e = 0; e < 4; ++e) {
      p0[e] = (short)f2bf(v0[e]); p0[4 + e] = (short)f2bf(v1[e]);
      p1[e] = (short)f2bf(v2[e]); p1[4 + e] = (short)f2bf(v3[e]);
    }
    *(s16x8*)(hs + row * HSTR + c0 * 2) = p0;
    *(s16x8*)(hs + row * HSTR + c0 * 2 + 16) = p1;
  }
  __syncthreads();
  const int hread = j * HSTR + hi * 16;
  f32x4 acc[4][4] = {};   // [ug2][q]
#pragma unroll
  for (int kt = 0; kt < 8; ++kt) {
    const int k = kt * 32 + hi * 8;
    const s16x8 a = *(const s16x8*)(hs + hread + kt * 64);   // h[b=j][k] (B-frag)
#pragma unroll
    for (int ug2 = 0; ug2 < 4; ++ug2)
#pragma unroll
      for (int q = 0; q < 4; ++q) {
        const s16x8 bw = *(const s16x8*)(wb + (((size_t)(q << 8) + wg * 64 + ug2 * 16 + j) << 8) + k);
        acc[ug2][q] = __builtin_amdgcn_mfma_f32_16x16x32_bf16(bw, a, acc[ug2][q], 0, 0, 0);
      }
  }
#pragma unroll
  for (int ug2 = 0; ug2 < 4; ++ug2) {
    const int sw = wg * 4 + ug2;
    const int uT = sw * 16 + hi * 4;
    s16x8 o0, o1;
#pragma unroll
    for (int r = 0; r < 4; ++r) {
      o0[r]     = (short)f2bf(acc[ug2][0][r] + bs[uT + r]);
      o0[4 + r] = (short)f2bf(acc[ug2][1][r] + bs[256 + uT + r]);
      o1[r]     = (short)f2bf(acc[ug2][2][r] + bs[512 + uT + r]);
      o1[4 + r] = (short)f2bf(acc[ug2][3][r] + bs[768 + uT + r]);
    }
    unsigned short* dst = gi + ((size_t)(t * 16 + sw) * 64 + lane) * 16;
    *(s16x8*)(dst) = o0;
    *(s16x8*)(dst + 8) = o1;
  }
}

// ============ fused pipeline (6 blocks): scan1{0,1} | gi2{2,3} | scan2{4,5} ============
// h exchange: TAGGED u64s — [v0:16][v1:16][tag:32], tag = step of the h value.
// Consumer polls the data itself (single LLC RTT); no flags, no vmcnt drain per step.

template <int ROLE>   // 0: layer1 (hb1 sc1 ys + 4-step credit); 1: layer2 (hout plain f32)
__device__ __forceinline__ void scan_tp(
    const unsigned short* __restrict__ gi,
    const unsigned short* __restrict__ whbL,  // Whh bf16 [1024][256]
    const int* __restrict__ lengths,
    unsigned short* __restrict__ hb1,
    float* __restrict__ hout,
    u64* hx,                                  // [4][16][128] tagged u64 exchange
    unsigned* mycred,                         // ROLE0: hb1 group credit
    unsigned* creds,                          // ROLE1: gf2 credits (u64 pair)
    int half)
{
  __shared__ __align__(16) char hl[4 * 8192];   // own-half h, 4 slots, XOR-swizzled
  const int tid  = threadIdx.x;
  const int lane = tid & 63;
  const int w    = tid >> 6;
  const int j    = lane & 15;    // batch
  const int hi   = lane >> 4;
  const int uB   = half * 128 + w * 16;
  const int myu  = uB + hi * 4;

  s16x8 wfr[32];   // A-frags: W[unit uB+j][k] for 4 gates x 8 k-tiles (128 VGPRs)
#pragma unroll
  for (int kt = 0; kt < 8; ++kt)
#pragma unroll
    for (int q = 0; q < 4; ++q)
      wfr[kt * 4 + q] =
          *(const s16x8*)(whbL + ((size_t)(q * 256 + uB + j) << 8) + kt * 32 + hi * 8);

  const int len = lengths[j];
  float c[4] = {};
  unsigned short hprev[4] = {};

  // h(0)=0 in own LDS slot 0 (hx slot 0 pre-zeroed by memset: values 0, tag 0)
  const int lws = ((j << 9) + (myu << 1)) ^ ((j & 7) << 4);
  *(u64*)(hl + lws) = 0;
  asm volatile("s_waitcnt lgkmcnt(0)" ::: "memory");
  __builtin_amdgcn_s_barrier();

  const unsigned short* gp = gi + ((size_t)(half * 8 + w) * 64 + lane) * 16;
  unsigned cred = 0;
  if (ROLE == 1) cred = wait2(creds, 8u, cred);   // BEFORE first gi touch
  s16x8 gE0, gE1, gO0, gO1;
  ld_g(gp, gE0, gE1);
  ld_g(gp + 16384, gO0, gO1);

  const int pbase = (1 - half) * 128;   // peer unit (k) range start

  for (int tg = 0; tg < T_STEPS; tg += 4) {
    if (ROLE == 1) {
      const unsigned target = (tg + 8 <= T_STEPS) ? (unsigned)(tg + 8) : (unsigned)T_STEPS;
      cred = wait2(creds, target, cred);
    }
#pragma unroll
    for (int ts = 0; ts < 4; ++ts) {
      const int t = tg + ts;
      s16x8& g0 = (ts & 1) ? gO0 : gE0;     // static even/odd register sets
      s16x8& g1 = (ts & 1) ? gO1 : gE1;
      const int cur = t & 3, nxt = (t + 1) & 3;

      f32x4 acc[4];
#pragma unroll
      for (int r = 0; r < 4; ++r) {
        acc[0][r] = bf2f((unsigned short)g0[r]);
        acc[1][r] = bf2f((unsigned short)g0[4 + r]);
        acc[2][r] = bf2f((unsigned short)g1[r]);
        acc[3][r] = bf2f((unsigned short)g1[4 + r]);
      }
      {  // 2-step-deep gi prefetch into the just-freed register set (plain cached)
        const int tn = (t + 2 < T_STEPS) ? t + 2 : T_STEPS - 1;
        ld_g(gp + (size_t)tn * 16384, g0, g1);
      }

      // ---- own-half MFMAs first (LDS) — overlaps peer-store propagation ----
#pragma unroll
      for (int p = 0; p < 4; ++p) {
        const int kt = half * 4 + p;
        const int k = half * 128 + p * 32 + hi * 8;
        const int off = cur * 8192 + (((j << 9) + (k << 1)) ^ ((j & 7) << 4));
        const s16x8 a = *(const s16x8*)(hl + off);
#pragma unroll
        for (int q = 0; q < 4; ++q)
          acc[q] = __builtin_amdgcn_mfma_f32_16x16x32_bf16(wfr[kt * 4 + q], a, acc[q], 0, 0, 0);
      }

      // ---- poll peer tagged data (data IS the flag: single LLC RTT) ----
      s16x8 avp[4];
      {
        const unsigned tagexp = (unsigned)t;
        for (;;) {
          bool ok = true;
#pragma unroll
          for (int p = 0; p < 4; ++p) {
            const int k = pbase + p * 32 + hi * 8;
            const u64* src = hx + (size_t)cur * 2048 + j * 128 + (k >> 1);
            const u64 a0 = ld64(src), a1 = ld64(src + 1);
            const u64 a2 = ld64(src + 2), a3 = ld64(src + 3);
            ok &= ((unsigned)(a0 >> 32) == tagexp) & ((unsigned)(a1 >> 32) == tagexp) &
                  ((unsigned)(a2 >> 32) == tagexp) & ((unsigned)(a3 >> 32) == tagexp);
            s16x8 v;
            v[0] = (short)a0; v[1] = (short)(a0 >> 16);
            v[2] = (short)a1; v[3] = (short)(a1 >> 16);
            v[4] = (short)a2; v[5] = (short)(a2 >> 16);
            v[6] = (short)a3; v[7] = (short)(a3 >> 16);
            avp[p] = v;
          }
          if (__ballot((int)ok) == ~0ull) break;
          __builtin_amdgcn_s_sleep(1);
        }
      }
#pragma unroll
      for (int p = 0; p < 4; ++p) {
        const int kt = (1 - half) * 4 + p;
#pragma unroll
        for (int q = 0; q < 4; ++q)
          acc[q] = __builtin_amdgcn_mfma_f32_16x16x32_bf16(wfr[kt * 4 + q], avp[p], acc[q], 0, 0, 0);
      }

      // ---- gates ----
      u64 hpk = 0, ypk = 0;
      f32x4 yv;
      const bool m = t < len;
#pragma unroll
      for (int r = 0; r < 4; ++r) {
        const float i_  = sigm(acc[0][r]);
        const float f_  = sigm(acc[1][r]);
        const float tg_ = tanh_f(acc[2][r]);
        const float o_  = sigm(acc[3][r]);
        const float cn = f_ * c[r] + i_ * tg_;
        const float hv = o_ * tanh_f(cn);
        c[r] = m ? cn : c[r];
        const unsigned short hb = m ? f2bf(hv) : hprev[r];
        hprev[r] = hb;
        hpk |= (u64)hb << (16 * r);
        if (ROLE == 0) ypk |= (u64)(m ? hb : (unsigned short)0) << (16 * r);
        else           yv[r] = m ? hv : 0.f;
      }
      // ---- publish h(t+1): LDS (own) + tagged sc1 u64s (peer); no drain, no flag ----
      *(u64*)(hl + nxt * 8192 + lws) = hpk;
      {
        const u64 tag = (u64)(unsigned)(t + 1) << 32;
        u64* dst = hx + (size_t)nxt * 2048 + j * 128 + (myu >> 1);
        st64(dst,     (hpk & 0xFFFFFFFFull) | tag);
        st64(dst + 1, (hpk >> 32)           | tag);
      }
      if (ROLE == 0) st64((u64*)hb1 + (((size_t)t * 4096 + j * 256 + myu) >> 2), ypk);
      else           *(f32x4*)(hout + ((size_t)t * 16 + j) * 256 + myu) = yv;

      if (ROLE == 0 && ts == 3) {   // 4-step hb1 credit (drain required once per group)
        asm volatile("s_waitcnt vmcnt(0) lgkmcnt(0)" ::: "memory");
        __builtin_amdgcn_s_barrier();
        if (tid == 0) stflag(mycred, (unsigned)(tg + 4));
      } else {
        asm volatile("s_waitcnt lgkmcnt(0)" ::: "memory");
        __builtin_amdgcn_s_barrier();
      }
      asm volatile("" ::: "memory");
    }
  }
}

// ---- gi2 producer CU: 8 waves, one 16-unit tile each, Wih2 slice in 128 VGPRs ----
__device__ __forceinline__ void gi2b(int cu,
    const unsigned short* __restrict__ hb1,
    const unsigned short* __restrict__ wb2,
    const float* __restrict__ bih2, const float* __restrict__ bhh2,
    unsigned short* __restrict__ gf2,
    unsigned* creds_in, unsigned* mycred)
{
  const int tid = threadIdx.x;
  const int lane = tid & 63;
  const int w = tid >> 6;
  const int j = lane & 15;
  const int hi = lane >> 4;
  const int sw = cu * 8 + w;

  s16x8 wfr[32];
  float bsum[4][4];
#pragma unroll
  for (int kt = 0; kt < 8; ++kt)
#pragma unroll
    for (int q = 0; q < 4; ++q)
      wfr[kt * 4 + q] =
          *(const s16x8*)(wb2 + ((size_t)(q * 256 + sw * 16 + j) << 8) + kt * 32 + hi * 8);
#pragma unroll
  for (int q = 0; q < 4; ++q)
#pragma unroll
    for (int r = 0; r < 4; ++r) {
      const int col = q * 256 + sw * 16 + hi * 4 + r;
      bsum[q][r] = bih2[col] + bhh2[col];
    }

  unsigned cred = 0;
  for (int tg = 0; tg < T_STEPS; tg += 4) {
    cred = wait2(creds_in, (unsigned)(tg + 4), cred);
#pragma unroll
    for (int ts = 0; ts < 4; ++ts) {
      const int t = tg + ts;
      const unsigned short* ab = hb1 + (size_t)t * 4096 + j * 256 + hi * 8;
      s16x8 av[8];
#pragma unroll
      for (int kt = 0; kt < 8; ++kt) av[kt] = *(const s16x8*)(ab + kt * 32);  // plain (credited)
      f32x4 acc[4];
#pragma unroll
      for (int q = 0; q < 4; ++q)
#pragma unroll
        for (int r = 0; r < 4; ++r) acc[q][r] = bsum[q][r];
#pragma unroll
      for (int kt = 0; kt < 8; ++kt)
#pragma unroll
        for (int q = 0; q < 4; ++q)
          acc[q] = __builtin_amdgcn_mfma_f32_16x16x32_bf16(wfr[kt * 4 + q], av[kt], acc[q], 0, 0, 0);
      u64 p0 = 0, q0 = 0, p1 = 0, q1 = 0;
#pragma unroll
      for (int r = 0; r < 4; ++r) {
        p0 |= (u64)f2bf(acc[0][r]) << (16 * r);
        q0 |= (u64)f2bf(acc[1][r]) << (16 * r);
        p1 |= (u64)f2bf(acc[2][r]) << (16 * r);
        q1 |= (u64)f2bf(acc[3][r]) << (16 * r);
      }
      u64* dst = (u64*)gf2 + ((size_t)(t * 16 + sw) * 64 + lane) * 4;
      st64(dst, p0); st64(dst + 1, q0); st64(dst + 2, p1); st64(dst + 3, q1);
    }
    asm volatile("s_waitcnt vmcnt(0)" ::: "memory");
    __builtin_amdgcn_s_barrier();
    if (tid == 0) stflag(mycred, (unsigned)(tg + 4));
  }
}

__global__ __launch_bounds__(512, 2) void fused_pipe(
    const unsigned short* __restrict__ gf1,
    const unsigned short* __restrict__ whb,   // Whh bf16 [2][1024][256]
    const unsigned short* __restrict__ wb,    // Wih bf16 [2][1024][256]
    const float* __restrict__ bih, const float* __restrict__ bhh,
    const int* __restrict__ lengths,
    unsigned short* hb1, unsigned short* gf2, float* hout2,
    u64* hx1, u64* hx2, unsigned* sync)
{
  // sync: [8,9]=hb1 creds, [12,13]=gf2 creds
  const int bid = blockIdx.x;
  if (bid == 0)
    scan_tp<0>(gf1, whb, lengths, hb1, nullptr, hx1, sync + 8, nullptr, 0);
  else if (bid == 1)
    scan_tp<0>(gf1, whb, lengths, hb1, nullptr, hx1, sync + 9, nullptr, 1);
  else if (bid == 2)
    gi2b(0, hb1, wb + 262144, bih + 1024, bhh + 1024, gf2, sync + 8, sync + 12);
  else if (bid == 3)
    gi2b(1, hb1, wb + 262144, bih + 1024, bhh + 1024, gf2, sync + 8, sync + 13);
  else if (bid == 4)
    scan_tp<1>(gf2, whb + 262144, lengths, nullptr, hout2, hx2, nullptr, sync + 12, 0);
  else
    scan_tp<1>(gf2, whb + 262144, lengths, nullptr, hout2, hx2, nullptr, sync + 12, 1);
}

// ---------------- output projection: y = mask ? h2 @ W2^T + b2 : 0 ----------------
__global__ __launch_bounds__(256) void outproj(const float* __restrict__ h2,
                                               const float* __restrict__ W2,
                                               const float* __restrict__ b2,
                                               const int* __restrict__ lengths,
                                               float* __restrict__ y) {
  __shared__ float w2s[OUTF][HID + 1];
  __shared__ float hs[8][HID + 1];
  const int tid = threadIdx.x;
  const int r0 = blockIdx.x * 8;
  for (int i = tid; i < OUTF * HID; i += 256) w2s[i / HID][i % HID] = W2[i];
  for (int i = tid; i < 8 * HID; i += 256)
    hs[i / HID][i % HID] = h2[(size_t)(r0 + i / HID) * HID + (i % HID)];
  __syncthreads();
  for (int oi = tid; oi < 8 * OUTF; oi += 256) {
    const int r = oi / OUTF, o = oi % OUTF;
    const int row = r0 + r, t = row >> 4, b = row & 15;
    float acc = b2[o];
#pragma unroll 8
    for (int k = 0; k < HID; ++k) acc += hs[r][k] * w2s[o][k];
    y[(size_t)row * OUTF + o] = (t < lengths[b]) ? acc : 0.f;
  }
}

extern "C" void kernel_launch(void* const* d_in, const int* in_sizes, int n_in,
                              void* d_out, int out_size, void* d_ws, size_t ws_size,
                              hipStream_t stream) {
  const float* x      = (const float*)d_in[0];
  const int*   lengths= (const int*)d_in[1];
  const float* W1     = (const float*)d_in[2];
  const float* b1     = (const float*)d_in[3];
  const float* Wih    = (const float*)d_in[4];
  const float* Whh    = (const float*)d_in[5];
  const float* bih    = (const float*)d_in[6];
  const float* bhh    = (const float*)d_in[7];
  const float* W2     = (const float*)d_in[8];
  const float* b2     = (const float*)d_in[9];
  float* out = (float*)d_out;

  char* ws = (char*)d_ws;
  float*          h0   = (float*)(ws);                          // 32 MB
  unsigned short* gf1  = (unsigned short*)(ws + 33554432);      // 64 MB
  unsigned short* hb1  = (unsigned short*)(ws + 100663296);     // 16 MB
  unsigned short* gf2  = (unsigned short*)(ws + 117440512);     // 64 MB
  float*          h2o  = (float*)(ws + 184549376);              // 32 MB
  unsigned short* wb   = (unsigned short*)(ws + 218103808);     // 1 MB (Wih bf16)
  unsigned short* whb  = (unsigned short*)(ws + 219152384);     // 1 MB (Whh bf16)
  u64*            hx1  = (u64*)(ws + 220200960);                // 64 KB tagged exchange L1
  u64*            hx2  = (u64*)(ws + 220266496);                // 64 KB tagged exchange L2
  unsigned*       sync = (unsigned*)(ws + 220332032);           // credits

  wpack<<<256, 256, 0, stream>>>(Wih, wb);
  wpack<<<256, 256, 0, stream>>>(Whh, whb);
  inproj<<<2048, 256, 0, stream>>>(x, W1, b1, h0);
  gi_mfma<<<2048, 256, 0, stream>>>(h0, wb, bih, bhh, gf1);

  // zero hx1+hx2+sync: slot-0 tags=0 & h(0)=0 pre-published; credits=0
  hipMemsetAsync((void*)hx1, 0, 2 * 65536 + 1024, stream);
  fused_pipe<<<6, 512, 0, stream>>>(gf1, whb, wb, bih, bhh, lengths,
                                    hb1, gf2, h2o, hx1, hx2, sync);

  outproj<<<4096, 256, 0, stream>>>(h2o, W2, b2, lengths, out);
}

// Round 13
// 15588.033 us; speedup vs baseline: 1.0147x; 1.0147x over previous
//
#include <hip/hip_runtime.h>
#include <hip/hip_bf16.h>

#define T_STEPS 2048
#define HID 256
#define INF 72
#define OUTF 90
#define HSTR 528          // LDS h row stride for gi_mfma (bytes)
#define VT 32             // ug0 weight tiles per wave in VGPRs (128 regs)
#define LT 18             // ug1 weight tiles per wave in LDS (18KB x 8 = 144KB)

typedef __attribute__((ext_vector_type(4))) float f32x4;
typedef __attribute__((ext_vector_type(8))) short s16x8;
typedef unsigned long long u64;

__device__ __forceinline__ unsigned short f2bf(float f) {
  union { float f; unsigned u; } v; v.f = f;
  unsigned r = (v.u + 0x7FFFu + ((v.u >> 16) & 1u)) >> 16;   // RNE
  return (unsigned short)r;
}
__device__ __forceinline__ float bf2f(unsigned short s) {
  union { unsigned u; float f; } v; v.u = ((unsigned)s) << 16;
  return v.f;
}
__device__ __forceinline__ float sigm(float x) {
  return __builtin_amdgcn_rcpf(1.f + __builtin_amdgcn_exp2f(-1.44269504f * x));
}
__device__ __forceinline__ float tanh_f(float x) {
  return 1.f - 2.f * __builtin_amdgcn_rcpf(1.f + __builtin_amdgcn_exp2f(2.88539008f * x));
}

// ---- relaxed agent-scope (sc1) primitives — R8/R11-proven ----
__device__ __forceinline__ u64 ld64(const u64* p) {
  return __hip_atomic_load(p, __ATOMIC_RELAXED, __HIP_MEMORY_SCOPE_AGENT);
}
__device__ __forceinline__ void st64(u64* p, u64 v) {
  __hip_atomic_store(p, v, __ATOMIC_RELAXED, __HIP_MEMORY_SCOPE_AGENT);
}
__device__ __forceinline__ void stflag(unsigned* p, unsigned v) {
  __hip_atomic_store(p, v, __ATOMIC_RELAXED, __HIP_MEMORY_SCOPE_AGENT);
}
__device__ __forceinline__ unsigned ldflag(const unsigned* p) {
  return __hip_atomic_load(p, __ATOMIC_RELAXED, __HIP_MEMORY_SCOPE_AGENT);
}
__device__ __forceinline__ void waitflag(const unsigned* p, unsigned target) {
  while (ldflag(p) < target) __builtin_amdgcn_s_sleep(2);
}
__device__ __forceinline__ unsigned wait2(const unsigned* creds, unsigned target, unsigned cred) {
  const u64* cp = (const u64*)creds;
  while (cred < target) {
    u64 v = ld64(cp);
    unsigned a = (unsigned)v, b = (unsigned)(v >> 32);
    cred = a < b ? a : b;
    if (cred < target) __builtin_amdgcn_s_sleep(2);
  }
  return cred;
}
__device__ __forceinline__ s16x8 ld16B_sc1(const unsigned short* p) {
  union { u64 u[2]; s16x8 v; } x;
  const u64* q = (const u64*)p;
  x.u[0] = ld64(q); x.u[1] = ld64(q + 1);
  return x.v;
}
// one 32B gi record: ROLE0 = plain cached (prior-kernel gf1); ROLE1 = sc1 (live gf2)
template <int ROLE> __device__ __forceinline__ void ld_g(const unsigned short* p, s16x8& a, s16x8& b) {
  if constexpr (ROLE == 0) { a = *(const s16x8*)p; b = *(const s16x8*)(p + 8); }
  else {
    union { u64 u[2]; s16x8 v; } x, y;
    const u64* q = (const u64*)p;
    x.u[0] = ld64(q); x.u[1] = ld64(q + 1);
    y.u[0] = ld64(q + 2); y.u[1] = ld64(q + 3);
    a = x.v; b = y.v;
  }
}

// ---------------- input projection: h0 = relu(x @ W1^T + b1) ----------------
__global__ __launch_bounds__(256) void inproj(const float* __restrict__ x,
                                              const float* __restrict__ W1,
                                              const float* __restrict__ b1,
                                              float* __restrict__ h0) {
  __shared__ float w1s[HID][INF + 1];
  __shared__ float xs[16][INF];
  const int tid = threadIdx.x;
  const int r0 = blockIdx.x * 16;
  for (int i = tid; i < HID * INF; i += 256) w1s[i / INF][i % INF] = W1[i];
  for (int i = tid; i < 16 * INF; i += 256)
    xs[i / INF][i % INF] = x[(size_t)(r0 + i / INF) * INF + (i % INF)];
  __syncthreads();
  const float bj = b1[tid];
  for (int r = 0; r < 16; ++r) {
    float acc = bj;
#pragma unroll 8
    for (int k = 0; k < INF; ++k) acc += xs[r][k] * w1s[tid][k];
    h0[(size_t)(r0 + r) * HID + tid] = fmaxf(acc, 0.f);
  }
}

// ---------------- pack f32 -> bf16 ----------------
__global__ __launch_bounds__(256) void wpack(const float* __restrict__ w,
                                             unsigned short* __restrict__ o) {
  const size_t i = ((size_t)blockIdx.x * 256 + threadIdx.x) * 8;
  f32x4 a = *(const f32x4*)(w + i);
  f32x4 b = *(const f32x4*)(w + i + 4);
  s16x8 v;
#pragma unroll
  for (int e = 0; e < 4; ++e) { v[e] = (short)f2bf(a[e]); v[4 + e] = (short)f2bf(b[e]); }
  *(s16x8*)(o + i) = v;
}

// ------------- layer-1 gi GEMM (MFMA, swapped orientation): one block per t -------------
__global__ __launch_bounds__(256) void gi_mfma(const float* __restrict__ h,
                                               const unsigned short* __restrict__ wb,
                                               const float* __restrict__ bih,
                                               const float* __restrict__ bhh,
                                               unsigned short* __restrict__ gi) {
  __shared__ __align__(16) char hs[16 * HSTR];
  __shared__ float bs[1024];
  const int tid = threadIdx.x;
  const int t = blockIdx.x;
  const int lane = tid & 63;
  const int wg = tid >> 6;
  const int j = lane & 15;
  const int hi = lane >> 4;
  for (int i = tid; i < 1024; i += 256) bs[i] = bih[i] + bhh[i];
  {
    const int row = tid >> 4;
    const int c0 = (tid & 15) * 16;
    const float* src = h + ((size_t)t * 16 + row) * 256 + c0;
    f32x4 v0 = *(const f32x4*)(src);
    f32x4 v1 = *(const f32x4*)(src + 4);
    f32x4 v2 = *(const f32x4*)(src + 8);
    f32x4 v3 = *(const f32x4*)(src + 12);
    s16x8 p0, p1;
#pragma unroll
    for (int e = 0; e < 4; ++e) {
      p0[e] = (short)f2bf(v0[e]); p0[4 + e] = (short)f2bf(v1[e]);
      p1[e] = (short)f2bf(v2[e]); p1[4 + e] = (short)f2bf(v3[e]);
    }
    *(s16x8*)(hs + row * HSTR + c0 * 2) = p0;
    *(s16x8*)(hs + row * HSTR + c0 * 2 + 16) = p1;
  }
  __syncthreads();
  const int hread = j * HSTR + hi * 16;
  f32x4 acc[4][4] = {};   // [ug2][q]
#pragma unroll
  for (int kt = 0; kt < 8; ++kt) {
    const int k = kt * 32 + hi * 8;
    const s16x8 a = *(const s16x8*)(hs + hread + kt * 64);   // h[b=j][k] (B-frag)
#pragma unroll
    for (int ug2 = 0; ug2 < 4; ++ug2)
#pragma unroll
      for (int q = 0; q < 4; ++q) {
        const s16x8 bw = *(const s16x8*)(wb + (((size_t)(q << 8) + wg * 64 + ug2 * 16 + j) << 8) + k);
        acc[ug2][q] = __builtin_amdgcn_mfma_f32_16x16x32_bf16(bw, a, acc[ug2][q], 0, 0, 0);
      }
  }
#pragma unroll
  for (int ug2 = 0; ug2 < 4; ++ug2) {
    const int sw = wg * 4 + ug2;
    const int uT = sw * 16 + hi * 4;
    s16x8 o0, o1;
#pragma unroll
    for (int r = 0; r < 4; ++r) {
      o0[r]     = (short)f2bf(acc[ug2][0][r] + bs[uT + r]);
      o0[4 + r] = (short)f2bf(acc[ug2][1][r] + bs[256 + uT + r]);
      o1[r]     = (short)f2bf(acc[ug2][2][r] + bs[512 + uT + r]);
      o1[4 + r] = (short)f2bf(acc[ug2][3][r] + bs[768 + uT + r]);
    }
    unsigned short* dst = gi + ((size_t)(t * 16 + sw) * 64 + lane) * 16;
    *(s16x8*)(dst) = o0;
    *(s16x8*)(dst + 8) = o1;
  }
}

// ============ fused pipeline: scan1 | gi2a | gi2b | scan2 (1 CU each) + keepers ============
// Single-CU scan: zero cross-CU traffic per step. Weights: VT=32 in regs (ug0),
// LT=18 in LDS (ug1 kt0..3 + kt4 q0,q1), 14 streamed from L2 (ug1 kt4 q2..kt7).

#define SKT(i) (((50 + (i)) >> 2) - 8)
#define SQ(i)  ((50 + (i)) & 3)

template <int ROLE>   // 0: layer1 (hb1 sc1 ys + 4-step credit); 1: layer2 (hout plain, done at end)
__device__ __forceinline__ void scan_1cu(
    const unsigned short* __restrict__ gi,    // [T][16][64][16] fragment file
    const unsigned short* __restrict__ whbL,  // Whh bf16 [1024][256]
    const int* __restrict__ lengths,
    unsigned short* __restrict__ hb1,
    float* __restrict__ hout,
    unsigned* mycred,                         // ROLE0: credit; ROLE1: done flag
    unsigned* creds,                          // ROLE1: gf2 credits (u64 pair)
    char* smem)
{
  char* wl = smem;                 // 147456 B weight tiles
  char* hl = smem + 147456;        // 2 x 8192 B h double-buffer (XOR-swizzled)
  const int tid = threadIdx.x;
  const int lane = tid & 63;
  const int w = tid >> 6;
  const int j = lane & 15;    // batch
  const int hi = lane >> 4;

  // ---- preload weights ----
  s16x8 wfr[VT];
#pragma unroll
  for (int ug = 0; ug < 2; ++ug)
#pragma unroll
    for (int kt = 0; kt < 8; ++kt)
#pragma unroll
      for (int q = 0; q < 4; ++q) {
        const int tau = (ug * 8 + kt) * 4 + q;
        if (tau >= VT + LT) continue;
        const int row = q * 256 + w * 32 + ug * 16 + j;
        const s16x8 v = *(const s16x8*)(whbL + ((size_t)row << 8) + kt * 32 + hi * 8);
        if (tau < VT) wfr[tau] = v;
        else *(s16x8*)(wl + (w * LT + (tau - VT)) * 1024 + lane * 16) = v;
      }
  for (int i = tid; i < 2048; i += 512) ((float*)hl)[i] = 0.f;   // h slot 0 = 0

  const int len = lengths[j];
  float c[8] = {};
  unsigned short hprev[8] = {};
  __syncthreads();

  const unsigned short* gp = gi + ((size_t)(w * 2) * 64 + lane) * 16;  // record 2w (+1024 for 2w+1)
  const unsigned short* swp = whbL + (size_t)(w * 32 + 16 + j) * 256 + hi * 8;  // L2-stream base

  unsigned cred = 0;
  if (ROLE == 1) cred = wait2(creds, 8u, cred);   // BEFORE first gi touch
  s16x8 gE[4], gO[4];
  ld_g<ROLE>(gp, gE[0], gE[1]);
  ld_g<ROLE>(gp + 1024, gE[2], gE[3]);

  auto STEP = [&](int t, s16x8 (&gc)[4], s16x8 (&gn)[4]) {
    const int cur = t & 1, nxt = cur ^ 1;
    // issue next-step gi into the dead register set (lead = one full step)
    {
      const int tn = (t + 1 < T_STEPS) ? t + 1 : t;
      const unsigned short* np = gp + (size_t)tn * 16384;
      ld_g<ROLE>(np, gn[0], gn[1]);
      ld_g<ROLE>(np + 1024, gn[2], gn[3]);
    }
    // issue L2-stream batch 0 (tiles 50..54)
    s16x8 gw[14];
#pragma unroll
    for (int i = 0; i < 5; ++i) gw[i] = *(const s16x8*)(swp + SQ(i) * 65536 + SKT(i) * 32);

    f32x4 acc0[4], acc1[4];
#pragma unroll
    for (int r = 0; r < 4; ++r) {
      acc0[0][r] = bf2f((unsigned short)gc[0][r]);
      acc0[1][r] = bf2f((unsigned short)gc[0][4 + r]);
      acc0[2][r] = bf2f((unsigned short)gc[1][r]);
      acc0[3][r] = bf2f((unsigned short)gc[1][4 + r]);
      acc1[0][r] = bf2f((unsigned short)gc[2][r]);
      acc1[1][r] = bf2f((unsigned short)gc[2][4 + r]);
      acc1[2][r] = bf2f((unsigned short)gc[3][r]);
      acc1[3][r] = bf2f((unsigned short)gc[3][4 + r]);
    }
#pragma unroll
    for (int kt = 0; kt < 8; ++kt) {
      const int hoff = cur * 8192 + (((j << 9) + ((kt * 32 + hi * 8) << 1)) ^ ((j & 7) << 4));
      const s16x8 a = *(const s16x8*)(hl + hoff);
#pragma unroll
      for (int q = 0; q < 4; ++q)
        acc0[q] = __builtin_amdgcn_mfma_f32_16x16x32_bf16(wfr[kt * 4 + q], a, acc0[q], 0, 0, 0);
#pragma unroll
      for (int q = 0; q < 4; ++q) {
        const int tau = 32 + kt * 4 + q;
        s16x8 bw;
        if (tau < VT + LT) bw = *(const s16x8*)(wl + (w * LT + (tau - VT)) * 1024 + lane * 16);
        else bw = gw[tau - 50];
        acc1[q] = __builtin_amdgcn_mfma_f32_16x16x32_bf16(bw, a, acc1[q], 0, 0, 0);
      }
      if (kt == 1) {
#pragma unroll
        for (int i = 5; i < 10; ++i) gw[i] = *(const s16x8*)(swp + SQ(i) * 65536 + SKT(i) * 32);
      }
      if (kt == 3) {
#pragma unroll
        for (int i = 10; i < 14; ++i) gw[i] = *(const s16x8*)(swp + SQ(i) * 65536 + SKT(i) * 32);
      }
    }
    // ---- gates for both unit-groups (lane-local) ----
    const bool m = t < len;
#pragma unroll
    for (int ug = 0; ug < 2; ++ug) {
      const int u = w * 32 + ug * 16 + hi * 4;
      u64 hpk = 0, ypk = 0;
      f32x4 yv;
#pragma unroll
      for (int r = 0; r < 4; ++r) {
        const int ci = ug * 4 + r;
        const float a0 = ug ? acc1[0][r] : acc0[0][r];
        const float a1 = ug ? acc1[1][r] : acc0[1][r];
        const float a2 = ug ? acc1[2][r] : acc0[2][r];
        const float a3 = ug ? acc1[3][r] : acc0[3][r];
        const float i_  = sigm(a0);
        const float f_  = sigm(a1);
        const float tg_ = tanh_f(a2);
        const float o_  = sigm(a3);
        const float cn = f_ * c[ci] + i_ * tg_;
        const float hv = o_ * tanh_f(cn);
        c[ci] = m ? cn : c[ci];
        const unsigned short hb = m ? f2bf(hv) : hprev[ci];
        hprev[ci] = hb;
        hpk |= (u64)hb << (16 * r);
        if (ROLE == 0) ypk |= (u64)(m ? hb : (unsigned short)0) << (16 * r);
        else           yv[r] = m ? hv : 0.f;
      }
      *(u64*)(hl + nxt * 8192 + (((j << 9) + (u << 1)) ^ ((j & 7) << 4))) = hpk;
      if (ROLE == 0) st64((u64*)hb1 + (((size_t)t * 4096 + j * 256 + u) >> 2), ypk);
      else           *(f32x4*)(hout + ((size_t)t * 16 + j) * 256 + u) = yv;
    }
    if (ROLE == 0 && (t & 3) == 3) {   // drain hb1 sc1 stores, post 4-step credit
      asm volatile("s_waitcnt vmcnt(0) lgkmcnt(0)" ::: "memory");
      __builtin_amdgcn_s_barrier();
      if (tid == 0) stflag(mycred, (unsigned)(t + 1));
    } else {
      asm volatile("s_waitcnt lgkmcnt(0)" ::: "memory");
      __builtin_amdgcn_s_barrier();
    }
    asm volatile("" ::: "memory");
  };

  for (int tg = 0; tg < T_STEPS; tg += 4) {
    if (ROLE == 1) {
      const unsigned target = (tg + 8 <= T_STEPS) ? (unsigned)(tg + 8) : (unsigned)T_STEPS;
      cred = wait2(creds, target, cred);
    }
    STEP(tg,     gE, gO);
    STEP(tg + 1, gO, gE);
    STEP(tg + 2, gE, gO);
    STEP(tg + 3, gO, gE);
  }
  if (ROLE == 1 && tid == 0) stflag(mycred, 1u);   // done flag for keepers
}

// ---- gi2 producer CU: 8 waves, one 16-unit tile each, Wih2 slice in 128 VGPRs ----
__device__ __forceinline__ void gi2b(int cu,
    const unsigned short* __restrict__ hb1,
    const unsigned short* __restrict__ wb2,
    const float* __restrict__ bih2, const float* __restrict__ bhh2,
    unsigned short* __restrict__ gf2,
    unsigned* cred_in, unsigned* mycred)
{
  const int tid = threadIdx.x;
  const int lane = tid & 63;
  const int w = tid >> 6;
  const int j = lane & 15;
  const int hi = lane >> 4;
  const int sw = cu * 8 + w;

  s16x8 wfr[32];
  float bsum[4][4];
#pragma unroll
  for (int kt = 0; kt < 8; ++kt)
#pragma unroll
    for (int q = 0; q < 4; ++q)
      wfr[kt * 4 + q] =
          *(const s16x8*)(wb2 + ((size_t)(q * 256 + sw * 16 + j) << 8) + kt * 32 + hi * 8);
#pragma unroll
  for (int q = 0; q < 4; ++q)
#pragma unroll
    for (int r = 0; r < 4; ++r) {
      const int col = q * 256 + sw * 16 + hi * 4 + r;
      bsum[q][r] = bih2[col] + bhh2[col];
    }

  for (int tg = 0; tg < T_STEPS; tg += 4) {
    waitflag(cred_in, (unsigned)(tg + 4));
#pragma unroll
    for (int ts = 0; ts < 4; ++ts) {
      const int t = tg + ts;
      const unsigned short* ab = hb1 + (size_t)t * 4096 + j * 256 + hi * 8;
      s16x8 av[8];
#pragma unroll
      for (int kt = 0; kt < 8; ++kt) av[kt] = ld16B_sc1(ab + kt * 32);
      f32x4 acc[4];
#pragma unroll
      for (int q = 0; q < 4; ++q)
#pragma unroll
        for (int r = 0; r < 4; ++r) acc[q][r] = bsum[q][r];
#pragma unroll
      for (int kt = 0; kt < 8; ++kt)
#pragma unroll
        for (int q = 0; q < 4; ++q)
          acc[q] = __builtin_amdgcn_mfma_f32_16x16x32_bf16(wfr[kt * 4 + q], av[kt], acc[q], 0, 0, 0);
      u64 p0 = 0, q0 = 0, p1 = 0, q1 = 0;
#pragma unroll
      for (int r = 0; r < 4; ++r) {
        p0 |= (u64)f2bf(acc[0][r]) << (16 * r);
        q0 |= (u64)f2bf(acc[1][r]) << (16 * r);
        p1 |= (u64)f2bf(acc[2][r]) << (16 * r);
        q1 |= (u64)f2bf(acc[3][r]) << (16 * r);
      }
      u64* dst = (u64*)gf2 + ((size_t)(t * 16 + sw) * 64 + lane) * 4;
      st64(dst, p0); st64(dst + 1, q0); st64(dst + 2, p1); st64(dst + 3, q1);
    }
    asm volatile("s_waitcnt vmcnt(0)" ::: "memory");
    __builtin_amdgcn_s_barrier();
    if (tid == 0) stflag(mycred, (unsigned)(tg + 4));
  }
}

// ---- keeper: clock-hold filler (dependent FMA spin + light HBM touch, capped) ----
__device__ __forceinline__ void keeper(const unsigned* donef, const float* junk) {
  float a = (float)(threadIdx.x + 1) * 1e-12f;
  const float b = 1.0000001f;
  for (int it = 0; it < 40000; ++it) {
    unsigned d = 0;
    if ((threadIdx.x & 63) == 0) d = ldflag(donef);
    d = (unsigned)__shfl((int)d, 0, 64);
    if (d) break;
    const int idx = (it * 12289 + (int)(blockIdx.x * 512u + threadIdx.x)) & 8388607;
    a += junk[idx] * 1e-30f;
#pragma unroll 32
    for (int i = 0; i < 2048; ++i) a = __builtin_fmaf(a, b, 1e-20f);
  }
  asm volatile("" :: "v"(a));
}

__global__ __launch_bounds__(512, 2) void fused_pipe(
    const unsigned short* __restrict__ gf1,
    const unsigned short* __restrict__ whb,   // Whh bf16 [2][1024][256]
    const unsigned short* __restrict__ wb,    // Wih bf16 [2][1024][256]
    const float* __restrict__ bih, const float* __restrict__ bhh,
    const int* __restrict__ lengths,
    unsigned short* hb1, unsigned short* gf2, float* hout2,
    const float* __restrict__ junk, unsigned* sync)
{
  // sync: [8]=scan1 credit, [12,13]=gi2 credits (u64 pair), [20]=done
  extern __shared__ char smem[];
  const int bid = blockIdx.x;
  if (bid == 0)
    scan_1cu<0>(gf1, whb, lengths, hb1, nullptr, sync + 8, nullptr, smem);
  else if (bid == 1)
    gi2b(0, hb1, wb + 262144, bih + 1024, bhh + 1024, gf2, sync + 8, sync + 12);
  else if (bid == 2)
    gi2b(1, hb1, wb + 262144, bih + 1024, bhh + 1024, gf2, sync + 8, sync + 13);
  else if (bid == 3)
    scan_1cu<1>(gf2, whb + 262144, lengths, nullptr, hout2, sync + 20, sync + 12, smem);
  else
    keeper(sync + 20, junk);
}

// ---------------- output projection: y = mask ? h2 @ W2^T + b2 : 0 ----------------
__global__ __launch_bounds__(256) void outproj(const float* __restrict__ h2,
                                               const float* __restrict__ W2,
                                               const float* __restrict__ b2,
                                               const int* __restrict__ lengths,
                                               float* __restrict__ y) {
  __shared__ float w2s[OUTF][HID + 1];
  __shared__ float hs[8][HID + 1];
  const int tid = threadIdx.x;
  const int r0 = blockIdx.x * 8;
  for (int i = tid; i < OUTF * HID; i += 256) w2s[i / HID][i % HID] = W2[i];
  for (int i = tid; i < 8 * HID; i += 256)
    hs[i / HID][i % HID] = h2[(size_t)(r0 + i / HID) * HID + (i % HID)];
  __syncthreads();
  for (int oi = tid; oi < 8 * OUTF; oi += 256) {
    const int r = oi / OUTF, o = oi % OUTF;
    const int row = r0 + r, t = row >> 4, b = row & 15;
    float acc = b2[o];
#pragma unroll 8
    for (int k = 0; k < HID; ++k) acc += hs[r][k] * w2s[o][k];
    y[(size_t)row * OUTF + o] = (t < lengths[b]) ? acc : 0.f;
  }
}

extern "C" void kernel_launch(void* const* d_in, const int* in_sizes, int n_in,
                              void* d_out, int out_size, void* d_ws, size_t ws_size,
                              hipStream_t stream) {
  const float* x      = (const float*)d_in[0];
  const int*   lengths= (const int*)d_in[1];
  const float* W1     = (const float*)d_in[2];
  const float* b1     = (const float*)d_in[3];
  const float* Wih    = (const float*)d_in[4];
  const float* Whh    = (const float*)d_in[5];
  const float* bih    = (const float*)d_in[6];
  const float* bhh    = (const float*)d_in[7];
  const float* W2     = (const float*)d_in[8];
  const float* b2     = (const float*)d_in[9];
  float* out = (float*)d_out;

  char* ws = (char*)d_ws;
  float*          h0   = (float*)(ws);                          // 32 MB (also keeper junk)
  unsigned short* gf1  = (unsigned short*)(ws + 33554432);      // 64 MB
  unsigned short* hb1  = (unsigned short*)(ws + 100663296);     // 16 MB
  unsigned short* gf2  = (unsigned short*)(ws + 117440512);     // 64 MB
  float*          h2o  = (float*)(ws + 184549376);              // 32 MB
  unsigned short* wb   = (unsigned short*)(ws + 218103808);     // 1 MB (Wih bf16)
  unsigned short* whb  = (unsigned short*)(ws + 219152384);     // 1 MB (Whh bf16)
  unsigned*       sync = (unsigned*)(ws + 220266496);           // credits/done

  hipFuncSetAttribute((const void*)fused_pipe,
                      hipFuncAttributeMaxDynamicSharedMemorySize, 163840);

  wpack<<<256, 256, 0, stream>>>(Wih, wb);
  wpack<<<256, 256, 0, stream>>>(Whh, whb);
  inproj<<<2048, 256, 0, stream>>>(x, W1, b1, h0);
  gi_mfma<<<2048, 256, 0, stream>>>(h0, wb, bih, bhh, gf1);

  hipMemsetAsync((void*)sync, 0, 1024, stream);
  fused_pipe<<<200, 512, 163840, stream>>>(gf1, whb, wb, bih, bhh, lengths,
                                           hb1, gf2, h2o, h0, sync);

  outproj<<<4096, 256, 0, stream>>>(h2o, W2, b2, lengths, out);
}

// Round 14
// 12731.241 us; speedup vs baseline: 1.2424x; 1.2244x over previous
//
#include <hip/hip_runtime.h>
#include <hip/hip_bf16.h>

#define T_STEPS 2048
#define HID 256
#define INF 72
#define OUTF 90
#define HSTR 528          // LDS h row stride for gi_mfma (bytes)
#define VT 40             // weight tiles in regs (160 VGPRs)
#define LT 18             // weight tiles in LDS per wave (18KB x 8 = 144KB)

typedef __attribute__((ext_vector_type(4))) float f32x4;
typedef __attribute__((ext_vector_type(8))) short s16x8;
typedef unsigned long long u64;

__device__ __forceinline__ unsigned short f2bf(float f) {
  union { float f; unsigned u; } v; v.f = f;
  unsigned r = (v.u + 0x7FFFu + ((v.u >> 16) & 1u)) >> 16;   // RNE
  return (unsigned short)r;
}
__device__ __forceinline__ float bf2f(unsigned short s) {
  union { unsigned u; float f; } v; v.u = ((unsigned)s) << 16;
  return v.f;
}
__device__ __forceinline__ float sigm(float x) {
  return __builtin_amdgcn_rcpf(1.f + __builtin_amdgcn_exp2f(-1.44269504f * x));
}
__device__ __forceinline__ float tanh_f(float x) {
  return 1.f - 2.f * __builtin_amdgcn_rcpf(1.f + __builtin_amdgcn_exp2f(2.88539008f * x));
}

// ---- relaxed agent-scope (sc1) primitives — R8/R11-proven ----
__device__ __forceinline__ u64 ld64(const u64* p) {
  return __hip_atomic_load(p, __ATOMIC_RELAXED, __HIP_MEMORY_SCOPE_AGENT);
}
__device__ __forceinline__ void st64(u64* p, u64 v) {
  __hip_atomic_store(p, v, __ATOMIC_RELAXED, __HIP_MEMORY_SCOPE_AGENT);
}
__device__ __forceinline__ void stflag(unsigned* p, unsigned v) {
  __hip_atomic_store(p, v, __ATOMIC_RELAXED, __HIP_MEMORY_SCOPE_AGENT);
}
__device__ __forceinline__ unsigned ldflag(const unsigned* p) {
  return __hip_atomic_load(p, __ATOMIC_RELAXED, __HIP_MEMORY_SCOPE_AGENT);
}
__device__ __forceinline__ void waitflag(const unsigned* p, unsigned target) {
  while (ldflag(p) < target) __builtin_amdgcn_s_sleep(2);
}
__device__ __forceinline__ unsigned wait2(const unsigned* creds, unsigned target, unsigned cred) {
  const u64* cp = (const u64*)creds;
  while (cred < target) {
    u64 v = ld64(cp);
    unsigned a = (unsigned)v, b = (unsigned)(v >> 32);
    cred = a < b ? a : b;
    if (cred < target) __builtin_amdgcn_s_sleep(2);
  }
  return cred;
}
__device__ __forceinline__ s16x8 ld16B_sc1(const unsigned short* p) {
  union { u64 u[2]; s16x8 v; } x;
  const u64* q = (const u64*)p;
  x.u[0] = ld64(q); x.u[1] = ld64(q + 1);
  return x.v;
}
// one 32B gi record: ROLE0 = plain cached (prior-kernel gf1); ROLE1 = sc1 (live gf2)
template <int ROLE> __device__ __forceinline__ void ld_g(const unsigned short* p, s16x8& a, s16x8& b) {
  if constexpr (ROLE == 0) { a = *(const s16x8*)p; b = *(const s16x8*)(p + 8); }
  else {
    union { u64 u[2]; s16x8 v; } x, y;
    const u64* q = (const u64*)p;
    x.u[0] = ld64(q); x.u[1] = ld64(q + 1);
    y.u[0] = ld64(q + 2); y.u[1] = ld64(q + 3);
    a = x.v; b = y.v;
  }
}

// ---------------- input projection: h0 = relu(x @ W1^T + b1) ----------------
__global__ __launch_bounds__(256) void inproj(const float* __restrict__ x,
                                              const float* __restrict__ W1,
                                              const float* __restrict__ b1,
                                              float* __restrict__ h0) {
  __shared__ float w1s[HID][INF + 1];
  __shared__ float xs[16][INF];
  const int tid = threadIdx.x;
  const int r0 = blockIdx.x * 16;
  for (int i = tid; i < HID * INF; i += 256) w1s[i / INF][i % INF] = W1[i];
  for (int i = tid; i < 16 * INF; i += 256)
    xs[i / INF][i % INF] = x[(size_t)(r0 + i / INF) * INF + (i % INF)];
  __syncthreads();
  const float bj = b1[tid];
  for (int r = 0; r < 16; ++r) {
    float acc = bj;
#pragma unroll 8
    for (int k = 0; k < INF; ++k) acc += xs[r][k] * w1s[tid][k];
    h0[(size_t)(r0 + r) * HID + tid] = fmaxf(acc, 0.f);
  }
}

// ---------------- pack f32 -> bf16 ----------------
__global__ __launch_bounds__(256) void wpack(const float* __restrict__ w,
                                             unsigned short* __restrict__ o) {
  const size_t i = ((size_t)blockIdx.x * 256 + threadIdx.x) * 8;
  f32x4 a = *(const f32x4*)(w + i);
  f32x4 b = *(const f32x4*)(w + i + 4);
  s16x8 v;
#pragma unroll
  for (int e = 0; e < 4; ++e) { v[e] = (short)f2bf(a[e]); v[4 + e] = (short)f2bf(b[e]); }
  *(s16x8*)(o + i) = v;
}

// ------------- layer-1 gi GEMM (MFMA, swapped orientation): one block per t -------------
__global__ __launch_bounds__(256) void gi_mfma(const float* __restrict__ h,
                                               const unsigned short* __restrict__ wb,
                                               const float* __restrict__ bih,
                                               const float* __restrict__ bhh,
                                               unsigned short* __restrict__ gi) {
  __shared__ __align__(16) char hs[16 * HSTR];
  __shared__ float bs[1024];
  const int tid = threadIdx.x;
  const int t = blockIdx.x;
  const int lane = tid & 63;
  const int wg = tid >> 6;
  const int j = lane & 15;
  const int hi = lane >> 4;
  for (int i = tid; i < 1024; i += 256) bs[i] = bih[i] + bhh[i];
  {
    const int row = tid >> 4;
    const int c0 = (tid & 15) * 16;
    const float* src = h + ((size_t)t * 16 + row) * 256 + c0;
    f32x4 v0 = *(const f32x4*)(src);
    f32x4 v1 = *(const f32x4*)(src + 4);
    f32x4 v2 = *(const f32x4*)(src + 8);
    f32x4 v3 = *(const f32x4*)(src + 12);
    s16x8 p0, p1;
#pragma unroll
    for (int e = 0; e < 4; ++e) {
      p0[e] = (short)f2bf(v0[e]); p0[4 + e] = (short)f2bf(v1[e]);
      p1[e] = (short)f2bf(v2[e]); p1[4 + e] = (short)f2bf(v3[e]);
    }
    *(s16x8*)(hs + row * HSTR + c0 * 2) = p0;
    *(s16x8*)(hs + row * HSTR + c0 * 2 + 16) = p1;
  }
  __syncthreads();
  const int hread = j * HSTR + hi * 16;
  f32x4 acc[4][4] = {};   // [ug2][q]
#pragma unroll
  for (int kt = 0; kt < 8; ++kt) {
    const int k = kt * 32 + hi * 8;
    const s16x8 a = *(const s16x8*)(hs + hread + kt * 64);   // h[b=j][k] (B-frag)
#pragma unroll
    for (int ug2 = 0; ug2 < 4; ++ug2)
#pragma unroll
      for (int q = 0; q < 4; ++q) {
        const s16x8 bw = *(const s16x8*)(wb + (((size_t)(q << 8) + wg * 64 + ug2 * 16 + j) << 8) + k);
        acc[ug2][q] = __builtin_amdgcn_mfma_f32_16x16x32_bf16(bw, a, acc[ug2][q], 0, 0, 0);
      }
  }
#pragma unroll
  for (int ug2 = 0; ug2 < 4; ++ug2) {
    const int sw = wg * 4 + ug2;
    const int uT = sw * 16 + hi * 4;
    s16x8 o0, o1;
#pragma unroll
    for (int r = 0; r < 4; ++r) {
      o0[r]     = (short)f2bf(acc[ug2][0][r] + bs[uT + r]);
      o0[4 + r] = (short)f2bf(acc[ug2][1][r] + bs[256 + uT + r]);
      o1[r]     = (short)f2bf(acc[ug2][2][r] + bs[512 + uT + r]);
      o1[4 + r] = (short)f2bf(acc[ug2][3][r] + bs[768 + uT + r]);
    }
    unsigned short* dst = gi + ((size_t)(t * 16 + sw) * 64 + lane) * 16;
    *(s16x8*)(dst) = o0;
    *(s16x8*)(dst + 8) = o1;
  }
}

// ============ fused pipeline (4 blocks): scan1 | gi2a | gi2b | scan2 ============
// Single-CU scan, spill-free: VT=40 tiles in regs, LT=18 in LDS, 6 streamed from
// L2 (24 regs live), acc processed sequentially per unit-group, gi single-buffered.

template <int ROLE>   // 0: layer1 (hb1 sc1 ys + 4-step credit); 1: layer2 (hout plain f32)
__device__ __forceinline__ void scan_1cu(
    const unsigned short* __restrict__ gi,    // [T][16][64][16] fragment file
    const unsigned short* __restrict__ whbL,  // Whh bf16 [1024][256]
    const int* __restrict__ lengths,
    unsigned short* __restrict__ hb1,
    float* __restrict__ hout,
    unsigned* mycred,                         // ROLE0: credit out
    unsigned* creds,                          // ROLE1: gf2 credits (u64 pair)
    char* smem)
{
  char* wl = smem;                 // 147456 B LDS weight tiles
  char* hl = smem + 147456;        // 2 x 8192 B h double-buffer (XOR-swizzled)
  const int tid = threadIdx.x;
  const int lane = tid & 63;
  const int w = tid >> 6;
  const int j = lane & 15;    // batch
  const int hi = lane >> 4;

  // ---- preload weights: tau<VT regs, VT..VT+LT-1 LDS, >=58 streamed per step ----
  s16x8 wfr[VT];
#pragma unroll
  for (int ug = 0; ug < 2; ++ug)
#pragma unroll
    for (int kt = 0; kt < 8; ++kt)
#pragma unroll
      for (int q = 0; q < 4; ++q) {
        const int tau = (ug * 8 + kt) * 4 + q;
        if (tau >= VT + LT) continue;
        const int row = q * 256 + w * 32 + ug * 16 + j;
        const s16x8 v = *(const s16x8*)(whbL + ((size_t)row << 8) + kt * 32 + hi * 8);
        if (tau < VT) wfr[tau] = v;
        else *(s16x8*)(wl + (w * LT + (tau - VT)) * 1024 + lane * 16) = v;
      }
  for (int i = tid; i < 4096; i += 512) ((float*)hl)[i] = 0.f;   // both h slots = 0

  const int len = lengths[j];
  float c[8] = {};
  unsigned short hprev[8] = {};
  __syncthreads();

  const unsigned short* gp = gi + ((size_t)(w * 2) * 64 + lane) * 16;
  const unsigned short* swp = whbL + (size_t)(w * 32 + 16 + j) * 256 + hi * 8;  // ug1 stream rows

  unsigned cred = 0;
  if (ROLE == 1) cred = wait2(creds, 8u, cred);   // BEFORE first gi touch
  s16x8 gc0, gc1, gc2, gc3;
  ld_g<ROLE>(gp, gc0, gc1);
  ld_g<ROLE>(gp + 1024, gc2, gc3);

  auto GATES = [&](int t, int ug, f32x4& a0, f32x4& a1, f32x4& a2, f32x4& a3, int nxt) {
    const bool m = t < len;
    const int u = w * 32 + ug * 16 + hi * 4;
    u64 hpk = 0, ypk = 0;
    f32x4 yv;
#pragma unroll
    for (int r = 0; r < 4; ++r) {
      const int ci = ug * 4 + r;
      const float i_  = sigm(a0[r]);
      const float f_  = sigm(a1[r]);
      const float tg_ = tanh_f(a2[r]);
      const float o_  = sigm(a3[r]);
      const float cn = f_ * c[ci] + i_ * tg_;
      const float hv = o_ * tanh_f(cn);
      c[ci] = m ? cn : c[ci];
      const unsigned short hb = m ? f2bf(hv) : hprev[ci];
      hprev[ci] = hb;
      hpk |= (u64)hb << (16 * r);
      if (ROLE == 0) ypk |= (u64)(m ? hb : (unsigned short)0) << (16 * r);
      else           yv[r] = m ? hv : 0.f;
    }
    *(u64*)(hl + nxt * 8192 + (((j << 9) + (u << 1)) ^ ((j & 7) << 4))) = hpk;
    if (ROLE == 0) st64((u64*)hb1 + (((size_t)t * 4096 + j * 256 + u) >> 2), ypk);
    else           *(f32x4*)(hout + ((size_t)t * 16 + j) * 256 + u) = yv;
  };

  auto STEP = [&](int t) {
    const int cur = t & 1, nxt = cur ^ 1;
    // stream the 6 L2 weight tiles (tau 58..63 = ug1 kt6 q2,q3 + kt7 q0..3)
    s16x8 gw0 = *(const s16x8*)(swp + 2 * 65536 + 6 * 32);
    s16x8 gw1 = *(const s16x8*)(swp + 3 * 65536 + 6 * 32);
    s16x8 gw2 = *(const s16x8*)(swp + 0 * 65536 + 7 * 32);
    s16x8 gw3 = *(const s16x8*)(swp + 1 * 65536 + 7 * 32);
    s16x8 gw4 = *(const s16x8*)(swp + 2 * 65536 + 7 * 32);
    s16x8 gw5 = *(const s16x8*)(swp + 3 * 65536 + 7 * 32);

    // ---- ug0: all weights in wfr[0..31] ----
    f32x4 acc[4];
#pragma unroll
    for (int r = 0; r < 4; ++r) {
      acc[0][r] = bf2f((unsigned short)gc0[r]);
      acc[1][r] = bf2f((unsigned short)gc0[4 + r]);
      acc[2][r] = bf2f((unsigned short)gc1[r]);
      acc[3][r] = bf2f((unsigned short)gc1[4 + r]);
    }
#pragma unroll
    for (int kt = 0; kt < 8; ++kt) {
      const int hoff = cur * 8192 + (((j << 9) + ((kt * 32 + hi * 8) << 1)) ^ ((j & 7) << 4));
      const s16x8 a = *(const s16x8*)(hl + hoff);
#pragma unroll
      for (int q = 0; q < 4; ++q)
        acc[q] = __builtin_amdgcn_mfma_f32_16x16x32_bf16(wfr[kt * 4 + q], a, acc[q], 0, 0, 0);
    }
    GATES(t, 0, acc[0], acc[1], acc[2], acc[3], nxt);

    // ---- ug1 init from gc2/gc3; gc dead -> prefetch gi[t+1] ----
#pragma unroll
    for (int r = 0; r < 4; ++r) {
      acc[0][r] = bf2f((unsigned short)gc2[r]);
      acc[1][r] = bf2f((unsigned short)gc2[4 + r]);
      acc[2][r] = bf2f((unsigned short)gc3[r]);
      acc[3][r] = bf2f((unsigned short)gc3[4 + r]);
    }
    {
      const int tn = (t + 1 < T_STEPS) ? t + 1 : t;
      const unsigned short* np = gp + (size_t)tn * 16384;
      ld_g<ROLE>(np, gc0, gc1);
      ld_g<ROLE>(np + 1024, gc2, gc3);
    }
    // ---- ug1: wfr[32..39] + LDS (tau 40..57) + streamed (58..63) ----
#pragma unroll
    for (int kt = 0; kt < 8; ++kt) {
      const int hoff = cur * 8192 + (((j << 9) + ((kt * 32 + hi * 8) << 1)) ^ ((j & 7) << 4));
      const s16x8 a = *(const s16x8*)(hl + hoff);
#pragma unroll
      for (int q = 0; q < 4; ++q) {
        const int tau = 32 + kt * 4 + q;
        s16x8 bw;
        if (tau < VT) bw = wfr[tau];
        else if (tau < VT + LT) bw = *(const s16x8*)(wl + (w * LT + (tau - VT)) * 1024 + lane * 16);
        else bw = (tau == 58) ? gw0 : (tau == 59) ? gw1 : (tau == 60) ? gw2
                : (tau == 61) ? gw3 : (tau == 62) ? gw4 : gw5;
        acc[q] = __builtin_amdgcn_mfma_f32_16x16x32_bf16(bw, a, acc[q], 0, 0, 0);
      }
    }
    GATES(t, 1, acc[0], acc[1], acc[2], acc[3], nxt);

    if (ROLE == 0 && (t & 3) == 3) {   // drain hb1 sc1 stores, post 4-step credit
      asm volatile("s_waitcnt vmcnt(0) lgkmcnt(0)" ::: "memory");
      __builtin_amdgcn_s_barrier();
      if (tid == 0) stflag(mycred, (unsigned)(t + 1));
    } else {
      asm volatile("s_waitcnt lgkmcnt(0)" ::: "memory");
      __builtin_amdgcn_s_barrier();
    }
    asm volatile("" ::: "memory");
  };

  for (int tg = 0; tg < T_STEPS; tg += 4) {
    if (ROLE == 1) {
      const unsigned target = (tg + 8 <= T_STEPS) ? (unsigned)(tg + 8) : (unsigned)T_STEPS;
      cred = wait2(creds, target, cred);
    }
    STEP(tg); STEP(tg + 1); STEP(tg + 2); STEP(tg + 3);
  }
}

// ---- gi2 producer CU: 8 waves, one 16-unit tile each, Wih2 slice in 128 VGPRs ----
__device__ __forceinline__ void gi2b(int cu,
    const unsigned short* __restrict__ hb1,
    const unsigned short* __restrict__ wb2,
    const float* __restrict__ bih2, const float* __restrict__ bhh2,
    unsigned short* __restrict__ gf2,
    unsigned* cred_in, unsigned* mycred)
{
  const int tid = threadIdx.x;
  const int lane = tid & 63;
  const int w = tid >> 6;
  const int j = lane & 15;
  const int hi = lane >> 4;
  const int sw = cu * 8 + w;

  s16x8 wfr[32];
  float bsum[4][4];
#pragma unroll
  for (int kt = 0; kt < 8; ++kt)
#pragma unroll
    for (int q = 0; q < 4; ++q)
      wfr[kt * 4 + q] =
          *(const s16x8*)(wb2 + ((size_t)(q * 256 + sw * 16 + j) << 8) + kt * 32 + hi * 8);
#pragma unroll
  for (int q = 0; q < 4; ++q)
#pragma unroll
    for (int r = 0; r < 4; ++r) {
      const int col = q * 256 + sw * 16 + hi * 4 + r;
      bsum[q][r] = bih2[col] + bhh2[col];
    }

  for (int tg = 0; tg < T_STEPS; tg += 4) {
    waitflag(cred_in, (unsigned)(tg + 4));
#pragma unroll
    for (int ts = 0; ts < 4; ++ts) {
      const int t = tg + ts;
      const unsigned short* ab = hb1 + (size_t)t * 4096 + j * 256 + hi * 8;
      s16x8 av[8];
#pragma unroll
      for (int kt = 0; kt < 8; ++kt) av[kt] = ld16B_sc1(ab + kt * 32);
      f32x4 acc[4];
#pragma unroll
      for (int q = 0; q < 4; ++q)
#pragma unroll
        for (int r = 0; r < 4; ++r) acc[q][r] = bsum[q][r];
#pragma unroll
      for (int kt = 0; kt < 8; ++kt)
#pragma unroll
        for (int q = 0; q < 4; ++q)
          acc[q] = __builtin_amdgcn_mfma_f32_16x16x32_bf16(wfr[kt * 4 + q], av[kt], acc[q], 0, 0, 0);
      u64 p0 = 0, q0 = 0, p1 = 0, q1 = 0;
#pragma unroll
      for (int r = 0; r < 4; ++r) {
        p0 |= (u64)f2bf(acc[0][r]) << (16 * r);
        q0 |= (u64)f2bf(acc[1][r]) << (16 * r);
        p1 |= (u64)f2bf(acc[2][r]) << (16 * r);
        q1 |= (u64)f2bf(acc[3][r]) << (16 * r);
      }
      u64* dst = (u64*)gf2 + ((size_t)(t * 16 + sw) * 64 + lane) * 4;
      st64(dst, p0); st64(dst + 1, q0); st64(dst + 2, p1); st64(dst + 3, q1);
    }
    asm volatile("s_waitcnt vmcnt(0)" ::: "memory");
    __builtin_amdgcn_s_barrier();
    if (tid == 0) stflag(mycred, (unsigned)(tg + 4));
  }
}

__global__ __launch_bounds__(512, 1) void fused_pipe(
    const unsigned short* __restrict__ gf1,
    const unsigned short* __restrict__ whb,   // Whh bf16 [2][1024][256]
    const unsigned short* __restrict__ wb,    // Wih bf16 [2][1024][256]
    const float* __restrict__ bih, const float* __restrict__ bhh,
    const int* __restrict__ lengths,
    unsigned short* hb1, unsigned short* gf2, float* hout2,
    unsigned* sync)
{
  // sync: [8]=scan1 credit, [12,13]=gi2 credits (u64 pair)
  extern __shared__ char smem[];
  const int bid = blockIdx.x;
  if (bid == 0)
    scan_1cu<0>(gf1, whb, lengths, hb1, nullptr, sync + 8, nullptr, smem);
  else if (bid == 1)
    gi2b(0, hb1, wb + 262144, bih + 1024, bhh + 1024, gf2, sync + 8, sync + 12);
  else if (bid == 2)
    gi2b(1, hb1, wb + 262144, bih + 1024, bhh + 1024, gf2, sync + 8, sync + 13);
  else
    scan_1cu<1>(gf2, whb + 262144, lengths, nullptr, hout2, nullptr, sync + 12, smem);
}

// ---------------- output projection: y = mask ? h2 @ W2^T + b2 : 0 ----------------
__global__ __launch_bounds__(256) void outproj(const float* __restrict__ h2,
                                               const float* __restrict__ W2,
                                               const float* __restrict__ b2,
                                               const int* __restrict__ lengths,
                                               float* __restrict__ y) {
  __shared__ float w2s[OUTF][HID + 1];
  __shared__ float hs[8][HID + 1];
  const int tid = threadIdx.x;
  const int r0 = blockIdx.x * 8;
  for (int i = tid; i < OUTF * HID; i += 256) w2s[i / HID][i % HID] = W2[i];
  for (int i = tid; i < 8 * HID; i += 256)
    hs[i / HID][i % HID] = h2[(size_t)(r0 + i / HID) * HID + (i % HID)];
  __syncthreads();
  for (int oi = tid; oi < 8 * OUTF; oi += 256) {
    const int r = oi / OUTF, o = oi % OUTF;
    const int row = r0 + r, t = row >> 4, b = row & 15;
    float acc = b2[o];
#pragma unroll 8
    for (int k = 0; k < HID; ++k) acc += hs[r][k] * w2s[o][k];
    y[(size_t)row * OUTF + o] = (t < lengths[b]) ? acc : 0.f;
  }
}

extern "C" void kernel_launch(void* const* d_in, const int* in_sizes, int n_in,
                              void* d_out, int out_size, void* d_ws, size_t ws_size,
                              hipStream_t stream) {
  const float* x      = (const float*)d_in[0];
  const int*   lengths= (const int*)d_in[1];
  const float* W1     = (const float*)d_in[2];
  const float* b1     = (const float*)d_in[3];
  const float* Wih    = (const float*)d_in[4];
  const float* Whh    = (const float*)d_in[5];
  const float* bih    = (const float*)d_in[6];
  const float* bhh    = (const float*)d_in[7];
  const float* W2     = (const float*)d_in[8];
  const float* b2     = (const float*)d_in[9];
  float* out = (float*)d_out;

  char* ws = (char*)d_ws;
  float*          h0   = (float*)(ws);                          // 32 MB
  unsigned short* gf1  = (unsigned short*)(ws + 33554432);      // 64 MB
  unsigned short* hb1  = (unsigned short*)(ws + 100663296);     // 16 MB
  unsigned short* gf2  = (unsigned short*)(ws + 117440512);     // 64 MB
  float*          h2o  = (float*)(ws + 184549376);              // 32 MB
  unsigned short* wb   = (unsigned short*)(ws + 218103808);     // 1 MB (Wih bf16)
  unsigned short* whb  = (unsigned short*)(ws + 219152384);     // 1 MB (Whh bf16)
  unsigned*       sync = (unsigned*)(ws + 220266496);           // credits

  hipFuncSetAttribute((const void*)fused_pipe,
                      hipFuncAttributeMaxDynamicSharedMemorySize, 163840);

  wpack<<<256, 256, 0, stream>>>(Wih, wb);
  wpack<<<256, 256, 0, stream>>>(Whh, whb);
  inproj<<<2048, 256, 0, stream>>>(x, W1, b1, h0);
  gi_mfma<<<2048, 256, 0, stream>>>(h0, wb, bih, bhh, gf1);

  hipMemsetAsync((void*)sync, 0, 1024, stream);
  fused_pipe<<<4, 512, 163840, stream>>>(gf1, whb, wb, bih, bhh, lengths,
                                         hb1, gf2, h2o, sync);

  outproj<<<4096, 256, 0, stream>>>(h2o, W2, b2, lengths, out);
}

// Round 15
// 11767.973 us; speedup vs baseline: 1.3441x; 1.0819x over previous
//
#include <hip/hip_runtime.h>
#include <hip/hip_bf16.h>

#define T_STEPS 2048
#define HID 256
#define INF 72
#define OUTF 90
#define HSTR 528          // LDS h row stride for gi_mfma (bytes)
#define VT 46             // weight tiles in regs (184 VGPRs)
#define LT 18             // weight tiles in LDS per wave (18KB x 8 = 144KB)

typedef __attribute__((ext_vector_type(4))) float f32x4;
typedef __attribute__((ext_vector_type(8))) short s16x8;
typedef unsigned long long u64;

__device__ __forceinline__ unsigned short f2bf(float f) {
  union { float f; unsigned u; } v; v.f = f;
  unsigned r = (v.u + 0x7FFFu + ((v.u >> 16) & 1u)) >> 16;   // RNE
  return (unsigned short)r;
}
__device__ __forceinline__ float bf2f(unsigned short s) {
  union { unsigned u; float f; } v; v.u = ((unsigned)s) << 16;
  return v.f;
}
__device__ __forceinline__ float sigm(float x) {
  return __builtin_amdgcn_rcpf(1.f + __builtin_amdgcn_exp2f(-1.44269504f * x));
}
__device__ __forceinline__ float tanh_f(float x) {
  return 1.f - 2.f * __builtin_amdgcn_rcpf(1.f + __builtin_amdgcn_exp2f(2.88539008f * x));
}

// ---- sc1 (agent-scope relaxed) WRITE-side primitives; consumers read PLAIN after credit ----
__device__ __forceinline__ u64 ld64(const u64* p) {
  return __hip_atomic_load(p, __ATOMIC_RELAXED, __HIP_MEMORY_SCOPE_AGENT);
}
__device__ __forceinline__ void st64(u64* p, u64 v) {
  __hip_atomic_store(p, v, __ATOMIC_RELAXED, __HIP_MEMORY_SCOPE_AGENT);
}
__device__ __forceinline__ void stflag(unsigned* p, unsigned v) {
  __hip_atomic_store(p, v, __ATOMIC_RELAXED, __HIP_MEMORY_SCOPE_AGENT);
}
__device__ __forceinline__ unsigned ldflag(const unsigned* p) {
  return __hip_atomic_load(p, __ATOMIC_RELAXED, __HIP_MEMORY_SCOPE_AGENT);
}
__device__ __forceinline__ void waitflag(const unsigned* p, unsigned target) {
  while (ldflag(p) < target) __builtin_amdgcn_s_sleep(2);
}
__device__ __forceinline__ unsigned wait2(const unsigned* creds, unsigned target, unsigned cred) {
  const u64* cp = (const u64*)creds;
  while (cred < target) {
    u64 v = ld64(cp);
    unsigned a = (unsigned)v, b = (unsigned)(v >> 32);
    cred = a < b ? a : b;
    if (cred < target) __builtin_amdgcn_s_sleep(2);
  }
  return cred;
}
// one 32B gi record, PLAIN cached (producer drained + credited, or prior kernel)
__device__ __forceinline__ void ld_g(const unsigned short* p, s16x8& a, s16x8& b) {
  a = *(const s16x8*)p; b = *(const s16x8*)(p + 8);
}

// ---------------- input projection: h0 = relu(x @ W1^T + b1) ----------------
__global__ __launch_bounds__(256) void inproj(const float* __restrict__ x,
                                              const float* __restrict__ W1,
                                              const float* __restrict__ b1,
                                              float* __restrict__ h0) {
  __shared__ float w1s[HID][INF + 1];
  __shared__ float xs[16][INF];
  const int tid = threadIdx.x;
  const int r0 = blockIdx.x * 16;
  for (int i = tid; i < HID * INF; i += 256) w1s[i / INF][i % INF] = W1[i];
  for (int i = tid; i < 16 * INF; i += 256)
    xs[i / INF][i % INF] = x[(size_t)(r0 + i / INF) * INF + (i % INF)];
  __syncthreads();
  const float bj = b1[tid];
  for (int r = 0; r < 16; ++r) {
    float acc = bj;
#pragma unroll 8
    for (int k = 0; k < INF; ++k) acc += xs[r][k] * w1s[tid][k];
    h0[(size_t)(r0 + r) * HID + tid] = fmaxf(acc, 0.f);
  }
}

// ---------------- pack f32 -> bf16 ----------------
__global__ __launch_bounds__(256) void wpack(const float* __restrict__ w,
                                             unsigned short* __restrict__ o) {
  const size_t i = ((size_t)blockIdx.x * 256 + threadIdx.x) * 8;
  f32x4 a = *(const f32x4*)(w + i);
  f32x4 b = *(const f32x4*)(w + i + 4);
  s16x8 v;
#pragma unroll
  for (int e = 0; e < 4; ++e) { v[e] = (short)f2bf(a[e]); v[4 + e] = (short)f2bf(b[e]); }
  *(s16x8*)(o + i) = v;
}

// ------------- layer-1 gi GEMM (MFMA, swapped orientation): one block per t -------------
__global__ __launch_bounds__(256) void gi_mfma(const float* __restrict__ h,
                                               const unsigned short* __restrict__ wb,
                                               const float* __restrict__ bih,
                                               const float* __restrict__ bhh,
                                               unsigned short* __restrict__ gi) {
  __shared__ __align__(16) char hs[16 * HSTR];
  __shared__ float bs[1024];
  const int tid = threadIdx.x;
  const int t = blockIdx.x;
  const int lane = tid & 63;
  const int wg = tid >> 6;
  const int j = lane & 15;
  const int hi = lane >> 4;
  for (int i = tid; i < 1024; i += 256) bs[i] = bih[i] + bhh[i];
  {
    const int row = tid >> 4;
    const int c0 = (tid & 15) * 16;
    const float* src = h + ((size_t)t * 16 + row) * 256 + c0;
    f32x4 v0 = *(const f32x4*)(src);
    f32x4 v1 = *(const f32x4*)(src + 4);
    f32x4 v2 = *(const f32x4*)(src + 8);
    f32x4 v3 = *(const f32x4*)(src + 12);
    s16x8 p0, p1;
#pragma unroll
    for (int e = 0; e < 4; ++e) {
      p0[e] = (short)f2bf(v0[e]); p0[4 + e] = (short)f2bf(v1[e]);
      p1[e] = (short)f2bf(v2[e]); p1[4 + e] = (short)f2bf(v3[e]);
    }
    *(s16x8*)(hs + row * HSTR + c0 * 2) = p0;
    *(s16x8*)(hs + row * HSTR + c0 * 2 + 16) = p1;
  }
  __syncthreads();
  const int hread = j * HSTR + hi * 16;
  f32x4 acc[4][4] = {};   // [ug2][q]
#pragma unroll
  for (int kt = 0; kt < 8; ++kt) {
    const int k = kt * 32 + hi * 8;
    const s16x8 a = *(const s16x8*)(hs + hread + kt * 64);   // h[b=j][k] (B-frag)
#pragma unroll
    for (int ug2 = 0; ug2 < 4; ++ug2)
#pragma unroll
      for (int q = 0; q < 4; ++q) {
        const s16x8 bw = *(const s16x8*)(wb + (((size_t)(q << 8) + wg * 64 + ug2 * 16 + j) << 8) + k);
        acc[ug2][q] = __builtin_amdgcn_mfma_f32_16x16x32_bf16(bw, a, acc[ug2][q], 0, 0, 0);
      }
  }
#pragma unroll
  for (int ug2 = 0; ug2 < 4; ++ug2) {
    const int sw = wg * 4 + ug2;
    const int uT = sw * 16 + hi * 4;
    s16x8 o0, o1;
#pragma unroll
    for (int r = 0; r < 4; ++r) {
      o0[r]     = (short)f2bf(acc[ug2][0][r] + bs[uT + r]);
      o0[4 + r] = (short)f2bf(acc[ug2][1][r] + bs[256 + uT + r]);
      o1[r]     = (short)f2bf(acc[ug2][2][r] + bs[512 + uT + r]);
      o1[4 + r] = (short)f2bf(acc[ug2][3][r] + bs[768 + uT + r]);
    }
    unsigned short* dst = gi + ((size_t)(t * 16 + sw) * 64 + lane) * 16;
    *(s16x8*)(dst) = o0;
    *(s16x8*)(dst + 8) = o1;
  }
}

// ============ fused pipeline (4 blocks): scan1 | gi2a | gi2b | scan2 ============
// Single-CU scan, ALL weights resident: VT=46 tiles in regs + LT=18 in LDS (=64).
// All cross-CU consumer reads are PLAIN cached after sc1-drain credits (R12 protocol).

template <int ROLE>   // 0: layer1 (hb1 sc1 ys + 4-step credit); 1: layer2 (hout plain f32)
__device__ __forceinline__ void scan_1cu(
    const unsigned short* __restrict__ gi,    // [T][16][64][16] fragment file
    const unsigned short* __restrict__ whbL,  // Whh bf16 [1024][256]
    const int* __restrict__ lengths,
    unsigned short* __restrict__ hb1,
    float* __restrict__ hout,
    unsigned* mycred,                         // ROLE0: credit out
    unsigned* creds,                          // ROLE1: gf2 credits (u64 pair)
    char* smem)
{
  char* wl = smem;                 // 147456 B LDS weight tiles
  char* hl = smem + 147456;        // 2 x 8192 B h double-buffer (XOR-swizzled)
  const int tid = threadIdx.x;
  const int lane = tid & 63;
  const int w = tid >> 6;
  const int j = lane & 15;    // batch
  const int hi = lane >> 4;

  // ---- preload weights: tau<VT regs, else LDS (all 64 tiles resident) ----
  s16x8 wfr[VT];
#pragma unroll
  for (int ug = 0; ug < 2; ++ug)
#pragma unroll
    for (int kt = 0; kt < 8; ++kt)
#pragma unroll
      for (int q = 0; q < 4; ++q) {
        const int tau = (ug * 8 + kt) * 4 + q;
        const int row = q * 256 + w * 32 + ug * 16 + j;
        const s16x8 v = *(const s16x8*)(whbL + ((size_t)row << 8) + kt * 32 + hi * 8);
        if (tau < VT) wfr[tau] = v;
        else *(s16x8*)(wl + (w * LT + (tau - VT)) * 1024 + lane * 16) = v;
      }
  for (int i = tid; i < 4096; i += 512) ((float*)hl)[i] = 0.f;   // both h slots = 0

  const int len = lengths[j];
  float c[8] = {};
  unsigned short hprev[8] = {};
  __syncthreads();

  const unsigned short* gp = gi + ((size_t)(w * 2) * 64 + lane) * 16;

  unsigned cred = 0;
  if (ROLE == 1) cred = wait2(creds, 8u, cred);   // BEFORE first gi touch
  s16x8 gc0, gc1, gc2, gc3;
  ld_g(gp, gc0, gc1);
  ld_g(gp + 1024, gc2, gc3);

  auto GATES = [&](int t, int ug, f32x4& a0, f32x4& a1, f32x4& a2, f32x4& a3, int nxt) {
    const bool m = t < len;
    const int u = w * 32 + ug * 16 + hi * 4;
    u64 hpk = 0, ypk = 0;
    f32x4 yv;
#pragma unroll
    for (int r = 0; r < 4; ++r) {
      const int ci = ug * 4 + r;
      const float i_  = sigm(a0[r]);
      const float f_  = sigm(a1[r]);
      const float tg_ = tanh_f(a2[r]);
      const float o_  = sigm(a3[r]);
      const float cn = f_ * c[ci] + i_ * tg_;
      const float hv = o_ * tanh_f(cn);
      c[ci] = m ? cn : c[ci];
      const unsigned short hb = m ? f2bf(hv) : hprev[ci];
      hprev[ci] = hb;
      hpk |= (u64)hb << (16 * r);
      if (ROLE == 0) ypk |= (u64)(m ? hb : (unsigned short)0) << (16 * r);
      else           yv[r] = m ? hv : 0.f;
    }
    *(u64*)(hl + nxt * 8192 + (((j << 9) + (u << 1)) ^ ((j & 7) << 4))) = hpk;
    if (ROLE == 0) st64((u64*)hb1 + (((size_t)t * 4096 + j * 256 + u) >> 2), ypk);
    else           *(f32x4*)(hout + ((size_t)t * 16 + j) * 256 + u) = yv;
  };

  auto STEP = [&](int t) {
    const int cur = t & 1, nxt = cur ^ 1;
    const int tn = (t + 1 < T_STEPS) ? t + 1 : t;

    // ---- ug0 init from gc0/gc1; they die -> prefetch gi[t+1] record 0 (plain, ~full-step lead)
    f32x4 acc[4];
#pragma unroll
    for (int r = 0; r < 4; ++r) {
      acc[0][r] = bf2f((unsigned short)gc0[r]);
      acc[1][r] = bf2f((unsigned short)gc0[4 + r]);
      acc[2][r] = bf2f((unsigned short)gc1[r]);
      acc[3][r] = bf2f((unsigned short)gc1[4 + r]);
    }
    ld_g(gp + (size_t)tn * 16384, gc0, gc1);

    // ---- ug0: all weights in wfr[0..31] ----
#pragma unroll
    for (int kt = 0; kt < 8; ++kt) {
      const int hoff = cur * 8192 + (((j << 9) + ((kt * 32 + hi * 8) << 1)) ^ ((j & 7) << 4));
      const s16x8 a = *(const s16x8*)(hl + hoff);
#pragma unroll
      for (int q = 0; q < 4; ++q)
        acc[q] = __builtin_amdgcn_mfma_f32_16x16x32_bf16(wfr[kt * 4 + q], a, acc[q], 0, 0, 0);
    }
    GATES(t, 0, acc[0], acc[1], acc[2], acc[3], nxt);

    // ---- ug1 init from gc2/gc3; they die -> prefetch gi[t+1] record 1 ----
#pragma unroll
    for (int r = 0; r < 4; ++r) {
      acc[0][r] = bf2f((unsigned short)gc2[r]);
      acc[1][r] = bf2f((unsigned short)gc2[4 + r]);
      acc[2][r] = bf2f((unsigned short)gc3[r]);
      acc[3][r] = bf2f((unsigned short)gc3[4 + r]);
    }
    ld_g(gp + (size_t)tn * 16384 + 1024, gc2, gc3);

    // ---- ug1: wfr[32..45] + LDS tiles (tau 46..63) ----
#pragma unroll
    for (int kt = 0; kt < 8; ++kt) {
      const int hoff = cur * 8192 + (((j << 9) + ((kt * 32 + hi * 8) << 1)) ^ ((j & 7) << 4));
      const s16x8 a = *(const s16x8*)(hl + hoff);
#pragma unroll
      for (int q = 0; q < 4; ++q) {
        const int tau = 32 + kt * 4 + q;
        s16x8 bw;
        if (tau < VT) bw = wfr[tau];
        else bw = *(const s16x8*)(wl + (w * LT + (tau - VT)) * 1024 + lane * 16);
        acc[q] = __builtin_amdgcn_mfma_f32_16x16x32_bf16(bw, a, acc[q], 0, 0, 0);
      }
    }
    GATES(t, 1, acc[0], acc[1], acc[2], acc[3], nxt);

    if (ROLE == 0 && (t & 3) == 3) {   // drain hb1 sc1 stores, post 4-step credit
      asm volatile("s_waitcnt vmcnt(0) lgkmcnt(0)" ::: "memory");
      __builtin_amdgcn_s_barrier();
      if (tid == 0) stflag(mycred, (unsigned)(t + 1));
    } else {
      asm volatile("s_waitcnt lgkmcnt(0)" ::: "memory");
      __builtin_amdgcn_s_barrier();
    }
    asm volatile("" ::: "memory");
  };

  for (int tg = 0; tg < T_STEPS; tg += 4) {
    if (ROLE == 1) {
      const unsigned target = (tg + 8 <= T_STEPS) ? (unsigned)(tg + 8) : (unsigned)T_STEPS;
      cred = wait2(creds, target, cred);
    }
    STEP(tg); STEP(tg + 1); STEP(tg + 2); STEP(tg + 3);
  }
}

// ---- gi2 producer CU: 8 waves, 2 record-tiles each, Wih2 slice in 128 VGPRs ----
__device__ __forceinline__ void gi2b(int cu,
    const unsigned short* __restrict__ hb1,
    const unsigned short* __restrict__ wb2,
    const float* __restrict__ bih2, const float* __restrict__ bhh2,
    unsigned short* __restrict__ gf2,
    unsigned* cred_in, unsigned* mycred)
{
  const int tid = threadIdx.x;
  const int lane = tid & 63;
  const int w = tid >> 6;
  const int j = lane & 15;
  const int hi = lane >> 4;
  const int sw = cu * 8 + w;

  s16x8 wfr[32];
  float bsum[4][4];
#pragma unroll
  for (int kt = 0; kt < 8; ++kt)
#pragma unroll
    for (int q = 0; q < 4; ++q)
      wfr[kt * 4 + q] =
          *(const s16x8*)(wb2 + ((size_t)(q * 256 + sw * 16 + j) << 8) + kt * 32 + hi * 8);
#pragma unroll
  for (int q = 0; q < 4; ++q)
#pragma unroll
    for (int r = 0; r < 4; ++r) {
      const int col = q * 256 + sw * 16 + hi * 4 + r;
      bsum[q][r] = bih2[col] + bhh2[col];
    }

  for (int tg = 0; tg < T_STEPS; tg += 4) {
    waitflag(cred_in, (unsigned)(tg + 4));
#pragma unroll
    for (int ts = 0; ts < 4; ++ts) {
      const int t = tg + ts;
      const unsigned short* ab = hb1 + (size_t)t * 4096 + j * 256 + hi * 8;
      s16x8 av[8];
#pragma unroll
      for (int kt = 0; kt < 8; ++kt) av[kt] = *(const s16x8*)(ab + kt * 32);  // plain (credited)
      f32x4 acc[4];
#pragma unroll
      for (int q = 0; q < 4; ++q)
#pragma unroll
        for (int r = 0; r < 4; ++r) acc[q][r] = bsum[q][r];
#pragma unroll
      for (int kt = 0; kt < 8; ++kt)
#pragma unroll
        for (int q = 0; q < 4; ++q)
          acc[q] = __builtin_amdgcn_mfma_f32_16x16x32_bf16(wfr[kt * 4 + q], av[kt], acc[q], 0, 0, 0);
      u64 p0 = 0, q0 = 0, p1 = 0, q1 = 0;
#pragma unroll
      for (int r = 0; r < 4; ++r) {
        p0 |= (u64)f2bf(acc[0][r]) << (16 * r);
        q0 |= (u64)f2bf(acc[1][r]) << (16 * r);
        p1 |= (u64)f2bf(acc[2][r]) << (16 * r);
        q1 |= (u64)f2bf(acc[3][r]) << (16 * r);
      }
      u64* dst = (u64*)gf2 + ((size_t)(t * 16 + sw) * 64 + lane) * 4;
      st64(dst, p0); st64(dst + 1, q0); st64(dst + 2, p1); st64(dst + 3, q1);
    }
    asm volatile("s_waitcnt vmcnt(0)" ::: "memory");
    __builtin_amdgcn_s_barrier();
    if (tid == 0) stflag(mycred, (unsigned)(tg + 4));
  }
}

__global__ __launch_bounds__(512, 1) void fused_pipe(
    const unsigned short* __restrict__ gf1,
    const unsigned short* __restrict__ whb,   // Whh bf16 [2][1024][256]
    const unsigned short* __restrict__ wb,    // Wih bf16 [2][1024][256]
    const float* __restrict__ bih, const float* __restrict__ bhh,
    const int* __restrict__ lengths,
    unsigned short* hb1, unsigned short* gf2, float* hout2,
    unsigned* sync)
{
  // sync: [8]=scan1 credit, [12,13]=gi2 credits (u64 pair)
  extern __shared__ char smem[];
  const int bid = blockIdx.x;
  if (bid == 0)
    scan_1cu<0>(gf1, whb, lengths, hb1, nullptr, sync + 8, nullptr, smem);
  else if (bid == 1)
    gi2b(0, hb1, wb + 262144, bih + 1024, bhh + 1024, gf2, sync + 8, sync + 12);
  else if (bid == 2)
    gi2b(1, hb1, wb + 262144, bih + 1024, bhh + 1024, gf2, sync + 8, sync + 13);
  else
    scan_1cu<1>(gf2, whb + 262144, lengths, nullptr, hout2, nullptr, sync + 12, smem);
}

// ---------------- output projection: y = mask ? h2 @ W2^T + b2 : 0 ----------------
__global__ __launch_bounds__(256) void outproj(const float* __restrict__ h2,
                                               const float* __restrict__ W2,
                                               const float* __restrict__ b2,
                                               const int* __restrict__ lengths,
                                               float* __restrict__ y) {
  __shared__ float w2s[OUTF][HID + 1];
  __shared__ float hs[8][HID + 1];
  const int tid = threadIdx.x;
  const int r0 = blockIdx.x * 8;
  for (int i = tid; i < OUTF * HID; i += 256) w2s[i / HID][i % HID] = W2[i];
  for (int i = tid; i < 8 * HID; i += 256)
    hs[i / HID][i % HID] = h2[(size_t)(r0 + i / HID) * HID + (i % HID)];
  __syncthreads();
  for (int oi = tid; oi < 8 * OUTF; oi += 256) {
    const int r = oi / OUTF, o = oi % OUTF;
    const int row = r0 + r, t = row >> 4, b = row & 15;
    float acc = b2[o];
#pragma unroll 8
    for (int k = 0; k < HID; ++k) acc += hs[r][k] * w2s[o][k];
    y[(size_t)row * OUTF + o] = (t < lengths[b]) ? acc : 0.f;
  }
}

extern "C" void kernel_launch(void* const* d_in, const int* in_sizes, int n_in,
                              void* d_out, int out_size, void* d_ws, size_t ws_size,
                              hipStream_t stream) {
  const float* x      = (const float*)d_in[0];
  const int*   lengths= (const int*)d_in[1];
  const float* W1     = (const float*)d_in[2];
  const float* b1     = (const float*)d_in[3];
  const float* Wih    = (const float*)d_in[4];
  const float* Whh    = (const float*)d_in[5];
  const float* bih    = (const float*)d_in[6];
  const float* bhh    = (const float*)d_in[7];
  const float* W2     = (const float*)d_in[8];
  const float* b2     = (const float*)d_in[9];
  float* out = (float*)d_out;

  char* ws = (char*)d_ws;
  float*          h0   = (float*)(ws);                          // 32 MB
  unsigned short* gf1  = (unsigned short*)(ws + 33554432);      // 64 MB
  unsigned short* hb1  = (unsigned short*)(ws + 100663296);     // 16 MB
  unsigned short* gf2  = (unsigned short*)(ws + 117440512);     // 64 MB
  float*          h2o  = (float*)(ws + 184549376);              // 32 MB
  unsigned short* wb   = (unsigned short*)(ws + 218103808);     // 1 MB (Wih bf16)
  unsigned short* whb  = (unsigned short*)(ws + 219152384);     // 1 MB (Whh bf16)
  unsigned*       sync = (unsigned*)(ws + 220266496);           // credits

  hipFuncSetAttribute((const void*)fused_pipe,
                      hipFuncAttributeMaxDynamicSharedMemorySize, 163840);

  wpack<<<256, 256, 0, stream>>>(Wih, wb);
  wpack<<<256, 256, 0, stream>>>(Whh, whb);
  inproj<<<2048, 256, 0, stream>>>(x, W1, b1, h0);
  gi_mfma<<<2048, 256, 0, stream>>>(h0, wb, bih, bhh, gf1);

  hipMemsetAsync((void*)sync, 0, 1024, stream);
  fused_pipe<<<4, 512, 163840, stream>>>(gf1, whb, wb, bih, bhh, lengths,
                                         hb1, gf2, h2o, sync);

  outproj<<<4096, 256, 0, stream>>>(h2o, W2, b2, lengths, out);
}